// Round 6
// baseline (516.823 us; speedup 1.0000x reference)
//
#include <hip/hip_runtime.h>
#include <math.h>

#define B_ 2
#define T_ 4096
#define E_ 1024
#define H_ 16
#define D_ 64
#define P_ 64
#define M_ 8
#define CH_ 256
#define NC_ 16
#define F_ 512
#define BH_ 32
#define BT_ 8192

// ---- workspace layout ----
static constexpr size_t SZ_BHTD = (size_t)B_ * H_ * T_ * D_;     // 8,388,608
static constexpr size_t SZ_PRF  = (size_t)B_ * H_ * T_ * M_;     // 1,048,576
static constexpr size_t SZ_KS   = (size_t)NC_ * BH_ * F_;        // 262,144
static constexpr size_t SZ_NRM  = (size_t)NC_ * BH_ * CH_;       // 131,072
static constexpr size_t SZ_KV_E = 33554432;                      // bf16 region

static constexpr size_t OFF_Q   = 0;
static constexpr size_t OFF_K   = OFF_Q + SZ_BHTD;
static constexpr size_t OFF_V   = OFF_K + SZ_BHTD;    // v bf16 (half used); woutb overlay later
static constexpr size_t OFF_FQ  = OFF_V + SZ_BHTD;
static constexpr size_t OFF_FK  = OFF_FQ + SZ_PRF;
static constexpr size_t OFF_KS  = OFF_FK + SZ_PRF;
static constexpr size_t OFF_NRM = OFF_KS + SZ_KS;
static constexpr size_t OFF_O   = OFF_NRM + SZ_NRM;
static constexpr size_t OFF_KV  = OFF_O + SZ_BHTD;
// total = OFF_KV*4 + SZ_KV_E*2 = 211,288,064 B (~201.5 MiB)

__device__ __forceinline__ float bf2f(unsigned short u) {
  union { unsigned u32; float f; } x; x.u32 = ((unsigned)u) << 16; return x.f;
}
__device__ __forceinline__ unsigned short f2bf(float f) {
  union { float f; unsigned u; } x; x.f = f;
  unsigned r = x.u + 0x7fffu + ((x.u >> 16) & 1u);
  return (unsigned short)(r >> 16);
}

typedef short v8s __attribute__((ext_vector_type(8)));
typedef float f32x4 __attribute__((ext_vector_type(4)));
#define LDSA 72   // GEMM LDS stride (bf16)

// ---------------------------------------------------------------------------
__global__ __launch_bounds__(256) void k_split_x(
    const float* __restrict__ x, unsigned short* __restrict__ hi,
    unsigned short* __restrict__ lo) {
  const size_t i4 = ((size_t)blockIdx.x * 256 + threadIdx.x) * 4;
  const float4 v = *(const float4*)(x + i4);
  ushort4 h, l;
  h.x = f2bf(v.x); l.x = f2bf(v.x - bf2f(h.x));
  h.y = f2bf(v.y); l.y = f2bf(v.y - bf2f(h.y));
  h.z = f2bf(v.z); l.z = f2bf(v.z - bf2f(h.z));
  h.w = f2bf(v.w); l.w = f2bf(v.w - bf2f(h.w));
  *(ushort4*)(hi + i4) = h;
  *(ushort4*)(lo + i4) = l;
}

__global__ __launch_bounds__(256) void k_cast_w(
    const float* __restrict__ w, unsigned short* __restrict__ wb) {
  const size_t i4 = ((size_t)blockIdx.x * 256 + threadIdx.x) * 4;
  const float4 v = *(const float4*)(w + i4);
  ushort4 h;
  h.x = f2bf(v.x); h.y = f2bf(v.y); h.z = f2bf(v.z); h.w = f2bf(v.w);
  *(ushort4*)(wb + i4) = h;
}

// ---------------------------------------------------------------------------
// QKV GEMM via MFMA. q/k: split-bf16 A (exact x), f32 out. v: hi-only, bf16 out.
// ---------------------------------------------------------------------------
__global__ __launch_bounds__(256) void k_qkv_mfma(
    const unsigned short* __restrict__ xhi, const unsigned short* __restrict__ xlo,
    const unsigned short* __restrict__ wb, const float* __restrict__ bias,
    float* __restrict__ qb, float* __restrict__ kb, unsigned short* __restrict__ vbf) {
  __shared__ __align__(16) unsigned short Ah[128 * LDSA];
  __shared__ __align__(16) unsigned short Al[128 * LDSA];
  __shared__ __align__(16) unsigned short Bs[128 * LDSA];
  const int bt0 = blockIdx.x * 128, j0 = blockIdx.y * 128;
  const bool do_lo = (blockIdx.y < 16);   // q/k sections only
  const int tid = threadIdx.x;
  const int lane = tid & 63, wave = tid >> 6;
  const int wm = (wave & 1) * 64, wn = (wave >> 1) * 64;
  const int col = lane & 15, quad = lane >> 4;
  f32x4 acc[4][4] = {};
  const int sr = tid >> 3, sg = tid & 7;

  for (int k0 = 0; k0 < E_; k0 += 64) {
    __syncthreads();
#pragma unroll
    for (int it = 0; it < 4; ++it) {
      const int r = it * 32 + sr;
      const size_t ga = (size_t)(bt0 + r) * E_ + k0 + sg * 8;
      *(v8s*)&Ah[r * LDSA + sg * 8] = *(const v8s*)(xhi + ga);
      if (do_lo) *(v8s*)&Al[r * LDSA + sg * 8] = *(const v8s*)(xlo + ga);
      *(v8s*)&Bs[r * LDSA + sg * 8] =
          *(const v8s*)(wb + (size_t)(j0 + r) * E_ + k0 + sg * 8);
    }
    __syncthreads();
#pragma unroll
    for (int kk = 0; kk < 2; ++kk) {
      v8s ah[4], al[4], bfr[4];
#pragma unroll
      for (int i = 0; i < 4; ++i) {
        const int mo = (wm + i * 16 + col) * LDSA + kk * 32 + quad * 8;
        ah[i] = *(const v8s*)&Ah[mo];
        if (do_lo) al[i] = *(const v8s*)&Al[mo];
        bfr[i] = *(const v8s*)&Bs[(wn + i * 16 + col) * LDSA + kk * 32 + quad * 8];
      }
#pragma unroll
      for (int i = 0; i < 4; ++i)
#pragma unroll
        for (int j = 0; j < 4; ++j) {
          acc[i][j] = __builtin_amdgcn_mfma_f32_16x16x32_bf16(ah[i], bfr[j], acc[i][j], 0, 0, 0);
          if (do_lo)
            acc[i][j] = __builtin_amdgcn_mfma_f32_16x16x32_bf16(al[i], bfr[j], acc[i][j], 0, 0, 0);
        }
    }
  }
#pragma unroll
  for (int j = 0; j < 4; ++j) {
    const int n = j0 + wn + j * 16 + col;
    const int sec = n >> 10, nn = n & 1023, h = nn >> 6, dd = nn & 63;
    const float bv = bias[n];
#pragma unroll
    for (int i = 0; i < 4; ++i) {
      const int mbase = bt0 + wm + i * 16 + quad * 4;
#pragma unroll
      for (int r = 0; r < 4; ++r) {
        const int m = mbase + r;
        const int b = m >> 12, t = m & (T_ - 1);
        const size_t oi = ((size_t)(b * H_ + h) * T_ + t) * D_ + dd;
        const float val = acc[i][j][r] + bv;
        if (sec == 0) qb[oi] = val;
        else if (sec == 1) kb[oi] = val;
        else vbf[oi] = f2bf(val);
      }
    }
  }
}

// ---------------------------------------------------------------------------
// Features via MFMA: l2norm rows (f32), split-xn A, B = [pw | omega] bf16.
// Epilogue: poly = c^2/8 -> pqb; prf = exp(clamp(c*sq2-s0))*scale -> fqb.
// Block = (bh, t-tile of 128). LDS 48.4 KB.
// ---------------------------------------------------------------------------
__global__ __launch_bounds__(256) void k_feat_mfma(
    const float* __restrict__ xin, const float* __restrict__ poly_w,
    const float* __restrict__ omega, const float* __restrict__ qnod,
    const float* __restrict__ qwt, unsigned short* __restrict__ pqb,
    unsigned short* __restrict__ fqb) {
  __shared__ __align__(16) unsigned short XH[128 * 72];  // 18,432 B
  __shared__ __align__(16) unsigned short XL[128 * 72];  // 18,432 B
  __shared__ __align__(16) unsigned short Bs[80 * 72];   // 11,520 B
  const int bh = blockIdx.x >> 5;
  const int t0 = (blockIdx.x & 31) * 128;
  const int h = bh & (H_ - 1);
  const int tid = threadIdx.x, lane = tid & 63, w = tid >> 6;
  const int col = lane & 15, quad = lane >> 4;
  const size_t rowB = (size_t)bh * T_ + t0;

  const float s0 = qnod[0];
  const float sq2 = sqrtf(fmaxf(2.f * s0, 0.f));
  const float scale = sqrtf(fmaxf(qwt[0], 0.f)) * 0.3535533905932738f;

  // l2norm + split-cast into LDS: wave w handles rows w*32..w*32+31, lane = d
  for (int rr = 0; rr < 32; ++rr) {
    const int t = w * 32 + rr;
    const float xv = xin[(rowB + t) * D_ + lane];
    float ss = xv * xv;
#pragma unroll
    for (int off = 32; off > 0; off >>= 1) ss += __shfl_xor(ss, off);
    const float rn = 1.0f / fmaxf(sqrtf(ss), 1e-12f);
    const float xn = xv * rn;
    const unsigned short hi = f2bf(xn);
    XH[t * 72 + lane] = hi;
    XL[t * 72 + lane] = f2bf(xn - bf2f(hi));
  }
  // stage B: rows 0..63 = pw^T, rows 64..71 = omega^T (rows 72..79 unused)
  {
    const int base = tid * 16;   // 4096 pw elems
#pragma unroll
    for (int j4 = 0; j4 < 4; ++j4) {
      const int idx = base + j4 * 4;
      const int d = idx >> 6, p = idx & 63;
      const float4 v = *(const float4*)(poly_w + (size_t)h * 4096 + idx);
      Bs[(p + 0) * 72 + d] = f2bf(v.x);
      Bs[(p + 1) * 72 + d] = f2bf(v.y);
      Bs[(p + 2) * 72 + d] = f2bf(v.z);
      Bs[(p + 3) * 72 + d] = f2bf(v.w);
    }
    if (tid < 128) {
      const int idx = tid * 4;
      const int d = idx >> 3, m0 = idx & 7;
      const float4 v = *(const float4*)(omega + (size_t)h * 512 + idx);
      Bs[(64 + m0 + 0) * 72 + d] = f2bf(v.x);
      Bs[(64 + m0 + 1) * 72 + d] = f2bf(v.y);
      Bs[(64 + m0 + 2) * 72 + d] = f2bf(v.z);
      Bs[(64 + m0 + 3) * 72 + d] = f2bf(v.w);
    }
  }
  __syncthreads();
  f32x4 acc[2][5] = {};
#pragma unroll
  for (int kk = 0; kk < 2; ++kk) {
    v8s ah[2], al[2];
#pragma unroll
    for (int i = 0; i < 2; ++i) {
      const int mo = ((2 * w + i) * 16 + col) * 72 + kk * 32 + quad * 8;
      ah[i] = *(const v8s*)&XH[mo];
      al[i] = *(const v8s*)&XL[mo];
    }
#pragma unroll
    for (int nt = 0; nt < 5; ++nt) {
      const v8s bb = *(const v8s*)&Bs[(nt * 16 + col) * 72 + kk * 32 + quad * 8];
#pragma unroll
      for (int i = 0; i < 2; ++i) {
        acc[i][nt] = __builtin_amdgcn_mfma_f32_16x16x32_bf16(ah[i], bb, acc[i][nt], 0, 0, 0);
        acc[i][nt] = __builtin_amdgcn_mfma_f32_16x16x32_bf16(al[i], bb, acc[i][nt], 0, 0, 0);
      }
    }
  }
  // epilogue
#pragma unroll
  for (int i = 0; i < 2; ++i) {
#pragma unroll
    for (int r = 0; r < 4; ++r) {
      const int t = (2 * w + i) * 16 + quad * 4 + r;
#pragma unroll
      for (int nt = 0; nt < 4; ++nt) {
        const float c = acc[i][nt][r];
        pqb[(rowB + t) * P_ + nt * 16 + col] = f2bf(c * c * 0.125f);
      }
      if (col < 8) {
        const float c = acc[i][4][r];
        const float z = fminf(fmaxf(c * sq2 - s0, -20.f), 20.f);
        fqb[(rowB + t) * M_ + col] = f2bf(expf(z) * scale);
      }
    }
  }
}

// ---------------------------------------------------------------------------
// Phase A via MFMA: kv[d][pm] = V^T(A) x KF^T(B, rank-1 generated). v is bf16.
// ---------------------------------------------------------------------------
__global__ __launch_bounds__(512) void k_phaseA(
    const unsigned short* __restrict__ pkb, const unsigned short* __restrict__ fkb,
    const unsigned short* __restrict__ vbf, unsigned short* __restrict__ kvch,
    float* __restrict__ ksum) {
  __shared__ __align__(16) unsigned short VT[64 * 72];
  __shared__ __align__(16) unsigned short pkT[64 * 72];
  __shared__ __align__(16) unsigned short fkT[8 * 72];
  const int bh = blockIdx.x & (BH_ - 1);
  const int c = blockIdx.x >> 5;
  const size_t rowC = (size_t)bh * T_ + (size_t)c * CH_;
  const int tid = threadIdx.x, lane = tid & 63, w = tid >> 6;
  const int col = lane & 15, quad = lane >> 4;
  const int nb = w * 64;
  f32x4 acc[4][4] = {};
  float ks[4] = {0.f, 0.f, 0.f, 0.f};

  for (int st = 0; st < 4; ++st) {
    const size_t t0 = rowC + st * 64;
    __syncthreads();
#pragma unroll
    for (int ps = 0; ps < 2; ++ps) {
      const int idx = ps * 512 + tid;
      const int t = idx >> 4, dg = (idx & 15) * 4;
      const ushort4 v = *(const ushort4*)(vbf + (t0 + t) * D_ + dg);
      VT[(dg + 0) * 72 + t] = v.x;
      VT[(dg + 1) * 72 + t] = v.y;
      VT[(dg + 2) * 72 + t] = v.z;
      VT[(dg + 3) * 72 + t] = v.w;
    }
    {
      const int t = tid >> 3, pg = (tid & 7) * 8;
      const v8s pv = *(const v8s*)(pkb + (t0 + t) * P_ + pg);
#pragma unroll
      for (int j = 0; j < 8; ++j) pkT[(pg + j) * 72 + t] = (unsigned short)pv[j];
    }
    if (tid < 64) {
      const v8s fv = *(const v8s*)(fkb + (t0 + tid) * M_);
#pragma unroll
      for (int j = 0; j < 8; ++j) fkT[j * 72 + tid] = (unsigned short)fv[j];
    }
    __syncthreads();
#pragma unroll
    for (int kk = 0; kk < 2; ++kk) {
      v8s a[4];
#pragma unroll
      for (int mt = 0; mt < 4; ++mt)
        a[mt] = *(const v8s*)&VT[(mt * 16 + col) * 72 + kk * 32 + quad * 8];
#pragma unroll
      for (int nt = 0; nt < 4; ++nt) {
        const int pm = nb + nt * 16 + col;
        const int p = pm >> 3, m8 = pm & 7;
        const v8s pkv = *(const v8s*)&pkT[p * 72 + kk * 32 + quad * 8];
        const v8s fkv = *(const v8s*)&fkT[m8 * 72 + kk * 32 + quad * 8];
        v8s bfrag;
        float kss = 0.f;
#pragma unroll
        for (int j = 0; j < 8; ++j) {
          const float v = bf2f((unsigned short)pkv[j]) * bf2f((unsigned short)fkv[j]);
          kss += v;
          bfrag[j] = (short)f2bf(v);
        }
        ks[nt] += kss;
#pragma unroll
        for (int mt = 0; mt < 4; ++mt)
          acc[mt][nt] = __builtin_amdgcn_mfma_f32_16x16x32_bf16(a[mt], bfrag, acc[mt][nt], 0, 0, 0);
      }
    }
  }
  const size_t base = (size_t)(c * BH_ + bh) * D_ * F_;
#pragma unroll
  for (int nt = 0; nt < 4; ++nt) {
    const int pm = nb + nt * 16 + col;
#pragma unroll
    for (int mt = 0; mt < 4; ++mt) {
#pragma unroll
      for (int r = 0; r < 4; ++r) {
        const int d = mt * 16 + quad * 4 + r;
        kvch[base + (size_t)d * F_ + pm] = f2bf(acc[mt][nt][r]);
      }
    }
    float kv_ = ks[nt];
    kv_ += __shfl_xor(kv_, 16);
    kv_ += __shfl_xor(kv_, 32);
    if (quad == 0) ksum[(size_t)(c * BH_ + bh) * F_ + pm] = kv_;
  }
}

// ---------------------------------------------------------------------------
__global__ __launch_bounds__(256) void k_scan_kv(unsigned short* __restrict__ kvch) {
  const size_t s = (size_t)blockIdx.x * 256 + threadIdx.x;
  const size_t stride = (size_t)BH_ * D_ * F_;
  unsigned short v[NC_];
#pragma unroll
  for (int c = 0; c < NC_; ++c) v[c] = kvch[(size_t)c * stride + s];
  float run = 0.f;
#pragma unroll
  for (int c = 0; c < NC_; ++c) {
    const float t = bf2f(v[c]);
    kvch[(size_t)c * stride + s] = f2bf(run);
    run += t;
  }
}

__global__ __launch_bounds__(256) void k_scan_ks(float* __restrict__ ksum) {
  const int s = blockIdx.x * 256 + threadIdx.x;
  const int stride = BH_ * F_;
  float v[NC_];
#pragma unroll
  for (int c = 0; c < NC_; ++c) v[c] = ksum[c * stride + s];
  float run = 0.f;
#pragma unroll
  for (int c = 0; c < NC_; ++c) {
    const float t = v[c];
    ksum[c * stride + s] = run;
    run += t;
  }
}

// ---------------------------------------------------------------------------
// Fused scores+intra via MFMA. v is bf16 now (pure-copy VT staging).
// ---------------------------------------------------------------------------
__global__ __launch_bounds__(256) void k_sintra(
    const unsigned short* __restrict__ pqb, const unsigned short* __restrict__ fqb,
    const unsigned short* __restrict__ pkb, const unsigned short* __restrict__ fkb,
    const unsigned short* __restrict__ vbf, float* __restrict__ obuf,
    float* __restrict__ nrmbuf) {
  __shared__ __align__(16) unsigned short S_lds[128 * 136];
  __shared__ __align__(16) unsigned short VT[64 * 136];
  __shared__ float fk_lds[128][8];
  const int bh = blockIdx.x & (BH_ - 1);
  const int tq = blockIdx.x >> 5;
  const int c = tq >> 1, h2 = tq & 1;
  const size_t rowT = (size_t)bh * T_ + (size_t)tq * 128;
  const size_t rowC = (size_t)bh * T_ + (size_t)c * CH_;
  const int tid = threadIdx.x, lane = tid & 63, w = tid >> 6;
  const int col = lane & 15, quad = lane >> 4;

  v8s bq[2][2];
  float fqr[2][8];
#pragma unroll
  for (int i = 0; i < 2; ++i) {
    const size_t qrow = rowT + (2 * w + i) * 16 + col;
    bq[i][0] = *(const v8s*)(pqb + qrow * P_ + quad * 8);
    bq[i][1] = *(const v8s*)(pqb + qrow * P_ + 32 + quad * 8);
    const v8s fv = *(const v8s*)(fqb + qrow * M_);
#pragma unroll
    for (int j = 0; j < 8; ++j) fqr[i][j] = bf2f((unsigned short)fv[j]);
  }
  f32x4 acc[2][4] = {};
  float rs[2] = {0.f, 0.f};

  const int vd = tid & 63, vg = tid >> 6;

  for (int sl = 0; sl <= h2; ++sl) {
    const size_t rowS = rowC + (size_t)sl * 128;
    __syncthreads();
    if (tid < 128) {
      const v8s fv = *(const v8s*)(fkb + (rowS + tid) * M_);
#pragma unroll
      for (int j = 0; j < 8; ++j) fk_lds[tid][j] = bf2f((unsigned short)fv[j]);
    }
#pragma unroll
    for (int j8 = 0; j8 < 4; ++j8) {
      const int s0 = vg * 32 + j8 * 8;
      v8s pv;
#pragma unroll
      for (int k = 0; k < 8; ++k)
        pv[k] = (short)vbf[(rowS + s0 + k) * D_ + vd];
      *(v8s*)&VT[vd * 136 + s0] = pv;
    }
    __syncthreads();
#pragma unroll
    for (int i = 0; i < 2; ++i) {
      const int tt = 2 * w + i;
      const int t_rel = h2 * 128 + tt * 16 + col;
      for (int si = 0; si < 8; ++si) {
        const size_t ar = rowS + si * 16 + col;
        const v8s a0 = *(const v8s*)(pkb + ar * P_ + quad * 8);
        const v8s a1 = *(const v8s*)(pkb + ar * P_ + 32 + quad * 8);
        f32x4 sp = {};
        sp = __builtin_amdgcn_mfma_f32_16x16x32_bf16(a0, bq[i][0], sp, 0, 0, 0);
        sp = __builtin_amdgcn_mfma_f32_16x16x32_bf16(a1, bq[i][1], sp, 0, 0, 0);
        ushort4 pk4;
        float partial = 0.f;
#pragma unroll
        for (int r = 0; r < 4; ++r) {
          const int s_in = si * 16 + quad * 4 + r;
          const float4 f0 = *(const float4*)&fk_lds[s_in][0];
          const float4 f1 = *(const float4*)&fk_lds[s_in][4];
          const float sm = f0.x * fqr[i][0] + f0.y * fqr[i][1] + f0.z * fqr[i][2] +
                           f0.w * fqr[i][3] + f1.x * fqr[i][4] + f1.y * fqr[i][5] +
                           f1.z * fqr[i][6] + f1.w * fqr[i][7];
          float val = sp[r] * sm;
          const int s_rel = sl * 128 + s_in;
          val = (s_rel <= t_rel) ? val : 0.f;
          partial += val;
          ((unsigned short*)&pk4)[r] = f2bf(val);
        }
        rs[i] += partial;
        *(ushort4*)&S_lds[(tt * 16 + col) * 136 + si * 16 + quad * 4] = pk4;
      }
    }
    __syncthreads();
#pragma unroll
    for (int i = 0; i < 2; ++i) {
      const int tt = 2 * w + i;
#pragma unroll
      for (int kk = 0; kk < 4; ++kk) {
        const v8s sa = *(const v8s*)&S_lds[(tt * 16 + col) * 136 + kk * 32 + quad * 8];
#pragma unroll
        for (int dt = 0; dt < 4; ++dt) {
          const v8s vb8 = *(const v8s*)&VT[(dt * 16 + col) * 136 + kk * 32 + quad * 8];
          acc[i][dt] = __builtin_amdgcn_mfma_f32_16x16x32_bf16(sa, vb8, acc[i][dt], 0, 0, 0);
        }
      }
    }
  }
#pragma unroll
  for (int i = 0; i < 2; ++i) {
#pragma unroll
    for (int dt = 0; dt < 4; ++dt) {
#pragma unroll
      for (int r = 0; r < 4; ++r) {
        const int t = (2 * w + i) * 16 + quad * 4 + r;
        obuf[(rowT + t) * D_ + dt * 16 + col] = acc[i][dt][r];
      }
    }
    rs[i] += __shfl_xor(rs[i], 16);
    rs[i] += __shfl_xor(rs[i], 32);
  }
  if (lane < 16) {
    const size_t nbase = (size_t)(c * BH_ + bh) * CH_ + h2 * 128;
    nrmbuf[nbase + (2 * w + 0) * 16 + lane] = rs[0];
    nrmbuf[nbase + (2 * w + 1) * 16 + lane] = rs[1];
  }
}

// ---------------------------------------------------------------------------
// Hist via MFMA (unchanged from round 5)
// ---------------------------------------------------------------------------
__global__ __launch_bounds__(256) void k_hist(
    const unsigned short* __restrict__ pqb, const unsigned short* __restrict__ fqb,
    const unsigned short* __restrict__ kvch, const float* __restrict__ ksum,
    const float* __restrict__ nrmbuf, const float* __restrict__ obuf,
    unsigned short* __restrict__ obf) {
  __shared__ __align__(16) unsigned short QF_lds[128 * 72];
  __shared__ __align__(16) unsigned short KV_lds[64 * 72];
  __shared__ float kp_lds[F_];
  __shared__ float nhs[128];
  const int half = blockIdx.x & 1;
  const int bh = (blockIdx.x >> 1) & (BH_ - 1);
  const int c = blockIdx.x >> 6;
  const int b = bh >> 4, h = bh & (H_ - 1);
  const int tid = threadIdx.x, lane = tid & 63, w = tid >> 6;
  const int col = lane & 15, quad = lane >> 4;
  const size_t rowQ = (size_t)bh * T_ + (size_t)c * CH_ + half * 128;
  const size_t kvbase = (size_t)(c * BH_ + bh) * D_ * F_;

  const int tr = tid >> 1, side = tid & 1;
  float fqr[8];
  {
    const v8s fv = *(const v8s*)(fqb + (rowQ + tr) * M_);
#pragma unroll
    for (int j = 0; j < 8; ++j) fqr[j] = bf2f((unsigned short)fv[j]);
    if (tid < 128)
      *(float4*)(&kp_lds[tid * 4]) =
          *(const float4*)(ksum + (size_t)(c * BH_ + bh) * F_ + tid * 4);
  }
  f32x4 acc[2][4] = {};
  float nh_part = 0.f;
  const int gr = tid & 7, d0 = tid >> 3;

  for (int pmt = 0; pmt < 8; ++pmt) {
    __syncthreads();
#pragma unroll
    for (int pp = 0; pp < 2; ++pp) {
      const int d = d0 + pp * 32;
      *(v8s*)&KV_lds[d * 72 + gr * 8] =
          *(const v8s*)(kvch + kvbase + (size_t)d * F_ + pmt * 64 + gr * 8);
    }
    {
      const v8s pq8 = *(const v8s*)(pqb + (rowQ + tr) * P_ + pmt * 8);
#pragma unroll
      for (int pp = 0; pp < 4; ++pp) {
        const int pl = side * 4 + pp;
        const float pqf = bf2f((unsigned short)pq8[pl]);
        const int kb_ = (pmt * 8 + pl) * 8;
        v8s o;
#pragma unroll
        for (int j = 0; j < 8; ++j) {
          const float v = pqf * fqr[j];
          nh_part += v * kp_lds[kb_ + j];
          o[j] = (short)f2bf(v);
        }
        *(v8s*)&QF_lds[tr * 72 + pl * 8] = o;
      }
    }
    __syncthreads();
#pragma unroll
    for (int kk = 0; kk < 2; ++kk) {
      v8s a[2], bb[4];
#pragma unroll
      for (int i = 0; i < 2; ++i)
        a[i] = *(const v8s*)&QF_lds[((2 * w + i) * 16 + col) * 72 + kk * 32 + quad * 8];
#pragma unroll
      for (int j = 0; j < 4; ++j)
        bb[j] = *(const v8s*)&KV_lds[(j * 16 + col) * 72 + kk * 32 + quad * 8];
#pragma unroll
      for (int i = 0; i < 2; ++i)
#pragma unroll
        for (int j = 0; j < 4; ++j)
          acc[i][j] = __builtin_amdgcn_mfma_f32_16x16x32_bf16(a[i], bb[j], acc[i][j], 0, 0, 0);
    }
  }
  {
    const float nh = nh_part + __shfl_xor(nh_part, 1);
    if (!(tid & 1)) nhs[tr] = nh;
  }
  __syncthreads();
  const size_t nbase = (size_t)(c * BH_ + bh) * CH_ + half * 128;
#pragma unroll
  for (int i = 0; i < 2; ++i) {
#pragma unroll
    for (int r = 0; r < 4; ++r) {
      const int t = (2 * w + i) * 16 + quad * 4 + r;
      const float nrm = nhs[t] + nrmbuf[nbase + t] + 1e-6f;
      const float rcp = 1.0f / nrm;
#pragma unroll
      for (int j = 0; j < 4; ++j) {
        const int d = j * 16 + col;
        const float val = (obuf[(rowQ + t) * D_ + d] + acc[i][j][r]) * rcp;
        obf[(size_t)(b * T_ + c * CH_ + half * 128 + t) * E_ + h * 64 + d] = f2bf(val);
      }
    }
  }
}

// ---------------------------------------------------------------------------
// Out GEMM via MFMA (unchanged)
// ---------------------------------------------------------------------------
__global__ __launch_bounds__(256) void k_out_mfma(
    const unsigned short* __restrict__ ob, const unsigned short* __restrict__ wb,
    const float* __restrict__ bias, float* __restrict__ out) {
  __shared__ __align__(16) unsigned short As[128 * LDSA];
  __shared__ __align__(16) unsigned short Bs[128 * LDSA];
  const int bt0 = blockIdx.x * 128, j0 = blockIdx.y * 128;
  const int tid = threadIdx.x;
  const int lane = tid & 63, wave = tid >> 6;
  const int wm = (wave & 1) * 64, wn = (wave >> 1) * 64;
  const int col = lane & 15, quad = lane >> 4;
  f32x4 acc[4][4] = {};
  const int sr = tid >> 3, sg = tid & 7;

  for (int k0 = 0; k0 < E_; k0 += 64) {
    __syncthreads();
#pragma unroll
    for (int it = 0; it < 4; ++it) {
      const int r = it * 32 + sr;
      *(v8s*)&As[r * LDSA + sg * 8] =
          *(const v8s*)(ob + (size_t)(bt0 + r) * E_ + k0 + sg * 8);
      *(v8s*)&Bs[r * LDSA + sg * 8] =
          *(const v8s*)(wb + (size_t)(j0 + r) * E_ + k0 + sg * 8);
    }
    __syncthreads();
#pragma unroll
    for (int kk = 0; kk < 2; ++kk) {
      v8s af[4], bfr[4];
#pragma unroll
      for (int i = 0; i < 4; ++i) {
        af[i] = *(const v8s*)&As[(wm + i * 16 + col) * LDSA + kk * 32 + quad * 8];
        bfr[i] = *(const v8s*)&Bs[(wn + i * 16 + col) * LDSA + kk * 32 + quad * 8];
      }
#pragma unroll
      for (int i = 0; i < 4; ++i)
#pragma unroll
        for (int j = 0; j < 4; ++j)
          acc[i][j] = __builtin_amdgcn_mfma_f32_16x16x32_bf16(af[i], bfr[j], acc[i][j], 0, 0, 0);
    }
  }
#pragma unroll
  for (int j = 0; j < 4; ++j) {
    const int n = j0 + wn + j * 16 + col;
    const float bv = bias[n];
#pragma unroll
    for (int i = 0; i < 4; ++i) {
      const int mbase = bt0 + wm + i * 16 + quad * 4;
#pragma unroll
      for (int r = 0; r < 4; ++r)
        out[(size_t)(mbase + r) * E_ + n] = acc[i][j][r] + bv;
    }
  }
}

// ---------------------------------------------------------------------------
extern "C" void kernel_launch(void* const* d_in, const int* in_sizes, int n_in,
                              void* d_out, int out_size, void* d_ws, size_t ws_size,
                              hipStream_t stream) {
  (void)in_sizes; (void)n_in; (void)out_size; (void)ws_size;
  const float* x      = (const float*)d_in[0];
  const float* qkv_w  = (const float*)d_in[1];
  const float* qkv_b  = (const float*)d_in[2];
  const float* out_w  = (const float*)d_in[3];
  const float* out_b  = (const float*)d_in[4];
  const float* omega  = (const float*)d_in[5];
  const float* poly_w = (const float*)d_in[6];
  const float* qnod   = (const float*)d_in[7];
  const float* qwt    = (const float*)d_in[8];
  float* ws = (float*)d_ws;
  float* qb   = ws + OFF_Q;
  float* kb   = ws + OFF_K;
  unsigned short* vbf = (unsigned short*)(ws + OFF_V);
  unsigned short* fqb = (unsigned short*)(ws + OFF_FQ);
  unsigned short* fkb = (unsigned short*)(ws + OFF_FK);
  float* ksb  = ws + OFF_KS;
  float* nrmb = ws + OFF_NRM;
  float* ob   = ws + OFF_O;
  unsigned short* kvb = (unsigned short*)(ws + OFF_KV);
  unsigned short* pqb = kvb + 16777216;
  unsigned short* pkb = pqb + SZ_BHTD;
  unsigned short* xhi  = kvb;
  unsigned short* xlo  = kvb + SZ_BHTD;
  unsigned short* wqkv = kvb + 2 * SZ_BHTD;
  unsigned short* obf   = (unsigned short*)kb;
  unsigned short* woutb = (unsigned short*)(ws + OFF_V);  // over dead v (post-sintra)
  float* outp = (float*)d_out;

  hipLaunchKernelGGL(k_split_x, dim3(8192), dim3(256), 0, stream, x, xhi, xlo);
  hipLaunchKernelGGL(k_cast_w, dim3(3072), dim3(256), 0, stream, qkv_w, wqkv);
  hipLaunchKernelGGL(k_qkv_mfma, dim3(BT_ / 128, 3 * E_ / 128), dim3(256), 0, stream,
                     xhi, xlo, wqkv, qkv_b, qb, kb, vbf);
  hipLaunchKernelGGL(k_feat_mfma, dim3(1024), dim3(256), 0, stream,
                     qb, poly_w, omega, qnod, qwt, pqb, fqb);
  hipLaunchKernelGGL(k_feat_mfma, dim3(1024), dim3(256), 0, stream,
                     kb, poly_w, omega, qnod, qwt, pkb, fkb);
  hipLaunchKernelGGL(k_phaseA, dim3(NC_ * BH_), dim3(512), 0, stream,
                     pkb, fkb, vbf, kvb, ksb);
  hipLaunchKernelGGL(k_scan_kv, dim3(4096), dim3(256), 0, stream, kvb);
  hipLaunchKernelGGL(k_scan_ks, dim3(64), dim3(256), 0, stream, ksb);
  hipLaunchKernelGGL(k_sintra, dim3(BH_ * 32), dim3(256), 0, stream,
                     pqb, fqb, pkb, fkb, vbf, ob, nrmb);
  hipLaunchKernelGGL(k_cast_w, dim3(1024), dim3(256), 0, stream, out_w, woutb);
  hipLaunchKernelGGL(k_hist, dim3(NC_ * BH_ * 2), dim3(256), 0, stream,
                     pqb, fqb, kvb, ksb, nrmb, ob, obf);
  hipLaunchKernelGGL(k_out_mfma, dim3(BT_ / 128, E_ / 128), dim3(256), 0, stream,
                     obf, woutb, out_b, outp);
}

// Round 7
// 470.756 us; speedup vs baseline: 1.0979x; 1.0979x over previous
//
#include <hip/hip_runtime.h>
#include <math.h>

#define B_ 2
#define T_ 4096
#define E_ 1024
#define H_ 16
#define D_ 64
#define P_ 64
#define M_ 8
#define CH_ 256
#define NC_ 16
#define F_ 512
#define BH_ 32
#define BT_ 8192

// ---- workspace layout ----
static constexpr size_t SZ_BHTD = (size_t)B_ * H_ * T_ * D_;     // 8,388,608
static constexpr size_t SZ_PRF  = (size_t)B_ * H_ * T_ * M_;     // 1,048,576
static constexpr size_t SZ_KS   = (size_t)NC_ * BH_ * F_;        // 262,144
static constexpr size_t SZ_NRM  = (size_t)NC_ * BH_ * CH_;       // 131,072
static constexpr size_t SZ_KV_E = 33554432;                      // bf16 region

static constexpr size_t OFF_Q   = 0;
static constexpr size_t OFF_K   = OFF_Q + SZ_BHTD;
static constexpr size_t OFF_V   = OFF_K + SZ_BHTD;    // v bf16 (half used); woutb overlay later
static constexpr size_t OFF_FQ  = OFF_V + SZ_BHTD;
static constexpr size_t OFF_FK  = OFF_FQ + SZ_PRF;
static constexpr size_t OFF_KS  = OFF_FK + SZ_PRF;
static constexpr size_t OFF_NRM = OFF_KS + SZ_KS;
static constexpr size_t OFF_O   = OFF_NRM + SZ_NRM;
static constexpr size_t OFF_KV  = OFF_O + SZ_BHTD;
// total = OFF_KV*4 + SZ_KV_E*2 = 211,288,064 B (~201.5 MiB)

__device__ __forceinline__ float bf2f(unsigned short u) {
  union { unsigned u32; float f; } x; x.u32 = ((unsigned)u) << 16; return x.f;
}
__device__ __forceinline__ unsigned short f2bf(float f) {
  union { float f; unsigned u; } x; x.f = f;
  unsigned r = x.u + 0x7fffu + ((x.u >> 16) & 1u);
  return (unsigned short)(r >> 16);
}

typedef short v8s __attribute__((ext_vector_type(8)));
typedef float f32x4 __attribute__((ext_vector_type(4)));
#define LDSA 72   // GEMM LDS stride (bf16)

// ---------------------------------------------------------------------------
__global__ __launch_bounds__(256) void k_split_x(
    const float* __restrict__ x, unsigned short* __restrict__ hi,
    unsigned short* __restrict__ lo) {
  const size_t i4 = ((size_t)blockIdx.x * 256 + threadIdx.x) * 4;
  const float4 v = *(const float4*)(x + i4);
  ushort4 h, l;
  h.x = f2bf(v.x); l.x = f2bf(v.x - bf2f(h.x));
  h.y = f2bf(v.y); l.y = f2bf(v.y - bf2f(h.y));
  h.z = f2bf(v.z); l.z = f2bf(v.z - bf2f(h.z));
  h.w = f2bf(v.w); l.w = f2bf(v.w - bf2f(h.w));
  *(ushort4*)(hi + i4) = h;
  *(ushort4*)(lo + i4) = l;
}

__global__ __launch_bounds__(256) void k_cast_w(
    const float* __restrict__ w, unsigned short* __restrict__ wb) {
  const size_t i4 = ((size_t)blockIdx.x * 256 + threadIdx.x) * 4;
  const float4 v = *(const float4*)(w + i4);
  ushort4 h;
  h.x = f2bf(v.x); h.y = f2bf(v.y); h.z = f2bf(v.z); h.w = f2bf(v.w);
  *(ushort4*)(wb + i4) = h;
}

// ---------------------------------------------------------------------------
// Q/K GEMM via MFMA, split-bf16 A (exact x), f32 out. Branch-free hot loop
// (round-5 schedule). grid = (64, 16): sections q (y<8) and k (y in 8..15).
// ---------------------------------------------------------------------------
__global__ __launch_bounds__(256) void k_qk_mfma(
    const unsigned short* __restrict__ xhi, const unsigned short* __restrict__ xlo,
    const unsigned short* __restrict__ wb, const float* __restrict__ bias,
    float* __restrict__ qb, float* __restrict__ kb) {
  __shared__ __align__(16) unsigned short Ah[128 * LDSA];
  __shared__ __align__(16) unsigned short Al[128 * LDSA];
  __shared__ __align__(16) unsigned short Bs[128 * LDSA];
  const int bt0 = blockIdx.x * 128, j0 = blockIdx.y * 128;
  const int tid = threadIdx.x;
  const int lane = tid & 63, wave = tid >> 6;
  const int wm = (wave & 1) * 64, wn = (wave >> 1) * 64;
  const int col = lane & 15, quad = lane >> 4;
  f32x4 acc[4][4] = {};
  const int sr = tid >> 3, sg = tid & 7;

  for (int k0 = 0; k0 < E_; k0 += 64) {
    __syncthreads();
#pragma unroll
    for (int it = 0; it < 4; ++it) {
      const int r = it * 32 + sr;
      const size_t ga = (size_t)(bt0 + r) * E_ + k0 + sg * 8;
      *(v8s*)&Ah[r * LDSA + sg * 8] = *(const v8s*)(xhi + ga);
      *(v8s*)&Al[r * LDSA + sg * 8] = *(const v8s*)(xlo + ga);
      *(v8s*)&Bs[r * LDSA + sg * 8] =
          *(const v8s*)(wb + (size_t)(j0 + r) * E_ + k0 + sg * 8);
    }
    __syncthreads();
#pragma unroll
    for (int kk = 0; kk < 2; ++kk) {
      v8s ah[4], al[4], bfr[4];
#pragma unroll
      for (int i = 0; i < 4; ++i) {
        const int mo = (wm + i * 16 + col) * LDSA + kk * 32 + quad * 8;
        ah[i] = *(const v8s*)&Ah[mo];
        al[i] = *(const v8s*)&Al[mo];
        bfr[i] = *(const v8s*)&Bs[(wn + i * 16 + col) * LDSA + kk * 32 + quad * 8];
      }
#pragma unroll
      for (int i = 0; i < 4; ++i)
#pragma unroll
        for (int j = 0; j < 4; ++j) {
          acc[i][j] = __builtin_amdgcn_mfma_f32_16x16x32_bf16(ah[i], bfr[j], acc[i][j], 0, 0, 0);
          acc[i][j] = __builtin_amdgcn_mfma_f32_16x16x32_bf16(al[i], bfr[j], acc[i][j], 0, 0, 0);
        }
    }
  }
#pragma unroll
  for (int j = 0; j < 4; ++j) {
    const int n = j0 + wn + j * 16 + col;
    const int sec = n >> 10, nn = n & 1023, h = nn >> 6, dd = nn & 63;
    float* dst = (sec == 0) ? qb : kb;
    const float bv = bias[n];
#pragma unroll
    for (int i = 0; i < 4; ++i) {
      const int mbase = bt0 + wm + i * 16 + quad * 4;
#pragma unroll
      for (int r = 0; r < 4; ++r) {
        const int m = mbase + r;
        const int b = m >> 12, t = m & (T_ - 1);
        dst[((size_t)(b * H_ + h) * T_ + t) * D_ + dd] = acc[i][j][r] + bv;
      }
    }
  }
}

// ---------------------------------------------------------------------------
// V GEMM via MFMA, hi-only bf16 A, bf16 out. Branch-free. grid = (64, 8).
// ---------------------------------------------------------------------------
__global__ __launch_bounds__(256) void k_v_mfma(
    const unsigned short* __restrict__ xhi, const unsigned short* __restrict__ wb,
    const float* __restrict__ bias, unsigned short* __restrict__ vbf) {
  __shared__ __align__(16) unsigned short Ah[128 * LDSA];
  __shared__ __align__(16) unsigned short Bs[128 * LDSA];
  const int bt0 = blockIdx.x * 128, j0 = blockIdx.y * 128;
  const int tid = threadIdx.x;
  const int lane = tid & 63, wave = tid >> 6;
  const int wm = (wave & 1) * 64, wn = (wave >> 1) * 64;
  const int col = lane & 15, quad = lane >> 4;
  f32x4 acc[4][4] = {};
  const int sr = tid >> 3, sg = tid & 7;

  for (int k0 = 0; k0 < E_; k0 += 64) {
    __syncthreads();
#pragma unroll
    for (int it = 0; it < 4; ++it) {
      const int r = it * 32 + sr;
      *(v8s*)&Ah[r * LDSA + sg * 8] =
          *(const v8s*)(xhi + (size_t)(bt0 + r) * E_ + k0 + sg * 8);
      *(v8s*)&Bs[r * LDSA + sg * 8] =
          *(const v8s*)(wb + (size_t)(2048 + j0 + r) * E_ + k0 + sg * 8);
    }
    __syncthreads();
#pragma unroll
    for (int kk = 0; kk < 2; ++kk) {
      v8s ah[4], bfr[4];
#pragma unroll
      for (int i = 0; i < 4; ++i) {
        ah[i] = *(const v8s*)&Ah[(wm + i * 16 + col) * LDSA + kk * 32 + quad * 8];
        bfr[i] = *(const v8s*)&Bs[(wn + i * 16 + col) * LDSA + kk * 32 + quad * 8];
      }
#pragma unroll
      for (int i = 0; i < 4; ++i)
#pragma unroll
        for (int j = 0; j < 4; ++j)
          acc[i][j] = __builtin_amdgcn_mfma_f32_16x16x32_bf16(ah[i], bfr[j], acc[i][j], 0, 0, 0);
    }
  }
#pragma unroll
  for (int j = 0; j < 4; ++j) {
    const int n = j0 + wn + j * 16 + col;   // 0..1023 within v section
    const int h = n >> 6, dd = n & 63;
    const float bv = bias[2048 + n];
#pragma unroll
    for (int i = 0; i < 4; ++i) {
      const int mbase = bt0 + wm + i * 16 + quad * 4;
#pragma unroll
      for (int r = 0; r < 4; ++r) {
        const int m = mbase + r;
        const int b = m >> 12, t = m & (T_ - 1);
        vbf[((size_t)(b * H_ + h) * T_ + t) * D_ + dd] = f2bf(acc[i][j][r] + bv);
      }
    }
  }
}

// ---------------------------------------------------------------------------
// Features via MFMA (unchanged from round 6)
// ---------------------------------------------------------------------------
__global__ __launch_bounds__(256) void k_feat_mfma(
    const float* __restrict__ xin, const float* __restrict__ poly_w,
    const float* __restrict__ omega, const float* __restrict__ qnod,
    const float* __restrict__ qwt, unsigned short* __restrict__ pqb,
    unsigned short* __restrict__ fqb) {
  __shared__ __align__(16) unsigned short XH[128 * 72];
  __shared__ __align__(16) unsigned short XL[128 * 72];
  __shared__ __align__(16) unsigned short Bs[80 * 72];
  const int bh = blockIdx.x >> 5;
  const int t0 = (blockIdx.x & 31) * 128;
  const int h = bh & (H_ - 1);
  const int tid = threadIdx.x, lane = tid & 63, w = tid >> 6;
  const int col = lane & 15, quad = lane >> 4;
  const size_t rowB = (size_t)bh * T_ + t0;

  const float s0 = qnod[0];
  const float sq2 = sqrtf(fmaxf(2.f * s0, 0.f));
  const float scale = sqrtf(fmaxf(qwt[0], 0.f)) * 0.3535533905932738f;

  for (int rr = 0; rr < 32; ++rr) {
    const int t = w * 32 + rr;
    const float xv = xin[(rowB + t) * D_ + lane];
    float ss = xv * xv;
#pragma unroll
    for (int off = 32; off > 0; off >>= 1) ss += __shfl_xor(ss, off);
    const float rn = 1.0f / fmaxf(sqrtf(ss), 1e-12f);
    const float xn = xv * rn;
    const unsigned short hi = f2bf(xn);
    XH[t * 72 + lane] = hi;
    XL[t * 72 + lane] = f2bf(xn - bf2f(hi));
  }
  {
    const int base = tid * 16;
#pragma unroll
    for (int j4 = 0; j4 < 4; ++j4) {
      const int idx = base + j4 * 4;
      const int d = idx >> 6, p = idx & 63;
      const float4 v = *(const float4*)(poly_w + (size_t)h * 4096 + idx);
      Bs[(p + 0) * 72 + d] = f2bf(v.x);
      Bs[(p + 1) * 72 + d] = f2bf(v.y);
      Bs[(p + 2) * 72 + d] = f2bf(v.z);
      Bs[(p + 3) * 72 + d] = f2bf(v.w);
    }
    if (tid < 128) {
      const int idx = tid * 4;
      const int d = idx >> 3, m0 = idx & 7;
      const float4 v = *(const float4*)(omega + (size_t)h * 512 + idx);
      Bs[(64 + m0 + 0) * 72 + d] = f2bf(v.x);
      Bs[(64 + m0 + 1) * 72 + d] = f2bf(v.y);
      Bs[(64 + m0 + 2) * 72 + d] = f2bf(v.z);
      Bs[(64 + m0 + 3) * 72 + d] = f2bf(v.w);
    }
  }
  __syncthreads();
  f32x4 acc[2][5] = {};
#pragma unroll
  for (int kk = 0; kk < 2; ++kk) {
    v8s ah[2], al[2];
#pragma unroll
    for (int i = 0; i < 2; ++i) {
      const int mo = ((2 * w + i) * 16 + col) * 72 + kk * 32 + quad * 8;
      ah[i] = *(const v8s*)&XH[mo];
      al[i] = *(const v8s*)&XL[mo];
    }
#pragma unroll
    for (int nt = 0; nt < 5; ++nt) {
      const v8s bb = *(const v8s*)&Bs[(nt * 16 + col) * 72 + kk * 32 + quad * 8];
#pragma unroll
      for (int i = 0; i < 2; ++i) {
        acc[i][nt] = __builtin_amdgcn_mfma_f32_16x16x32_bf16(ah[i], bb, acc[i][nt], 0, 0, 0);
        acc[i][nt] = __builtin_amdgcn_mfma_f32_16x16x32_bf16(al[i], bb, acc[i][nt], 0, 0, 0);
      }
    }
  }
#pragma unroll
  for (int i = 0; i < 2; ++i) {
#pragma unroll
    for (int r = 0; r < 4; ++r) {
      const int t = (2 * w + i) * 16 + quad * 4 + r;
#pragma unroll
      for (int nt = 0; nt < 4; ++nt) {
        const float c = acc[i][nt][r];
        pqb[(rowB + t) * P_ + nt * 16 + col] = f2bf(c * c * 0.125f);
      }
      if (col < 8) {
        const float c = acc[i][4][r];
        const float z = fminf(fmaxf(c * sq2 - s0, -20.f), 20.f);
        fqb[(rowB + t) * M_ + col] = f2bf(expf(z) * scale);
      }
    }
  }
}

// ---------------------------------------------------------------------------
// Phase A via MFMA (unchanged from round 6)
// ---------------------------------------------------------------------------
__global__ __launch_bounds__(512) void k_phaseA(
    const unsigned short* __restrict__ pkb, const unsigned short* __restrict__ fkb,
    const unsigned short* __restrict__ vbf, unsigned short* __restrict__ kvch,
    float* __restrict__ ksum) {
  __shared__ __align__(16) unsigned short VT[64 * 72];
  __shared__ __align__(16) unsigned short pkT[64 * 72];
  __shared__ __align__(16) unsigned short fkT[8 * 72];
  const int bh = blockIdx.x & (BH_ - 1);
  const int c = blockIdx.x >> 5;
  const size_t rowC = (size_t)bh * T_ + (size_t)c * CH_;
  const int tid = threadIdx.x, lane = tid & 63, w = tid >> 6;
  const int col = lane & 15, quad = lane >> 4;
  const int nb = w * 64;
  f32x4 acc[4][4] = {};
  float ks[4] = {0.f, 0.f, 0.f, 0.f};

  for (int st = 0; st < 4; ++st) {
    const size_t t0 = rowC + st * 64;
    __syncthreads();
#pragma unroll
    for (int ps = 0; ps < 2; ++ps) {
      const int idx = ps * 512 + tid;
      const int t = idx >> 4, dg = (idx & 15) * 4;
      const ushort4 v = *(const ushort4*)(vbf + (t0 + t) * D_ + dg);
      VT[(dg + 0) * 72 + t] = v.x;
      VT[(dg + 1) * 72 + t] = v.y;
      VT[(dg + 2) * 72 + t] = v.z;
      VT[(dg + 3) * 72 + t] = v.w;
    }
    {
      const int t = tid >> 3, pg = (tid & 7) * 8;
      const v8s pv = *(const v8s*)(pkb + (t0 + t) * P_ + pg);
#pragma unroll
      for (int j = 0; j < 8; ++j) pkT[(pg + j) * 72 + t] = (unsigned short)pv[j];
    }
    if (tid < 64) {
      const v8s fv = *(const v8s*)(fkb + (t0 + tid) * M_);
#pragma unroll
      for (int j = 0; j < 8; ++j) fkT[j * 72 + tid] = (unsigned short)fv[j];
    }
    __syncthreads();
#pragma unroll
    for (int kk = 0; kk < 2; ++kk) {
      v8s a[4];
#pragma unroll
      for (int mt = 0; mt < 4; ++mt)
        a[mt] = *(const v8s*)&VT[(mt * 16 + col) * 72 + kk * 32 + quad * 8];
#pragma unroll
      for (int nt = 0; nt < 4; ++nt) {
        const int pm = nb + nt * 16 + col;
        const int p = pm >> 3, m8 = pm & 7;
        const v8s pkv = *(const v8s*)&pkT[p * 72 + kk * 32 + quad * 8];
        const v8s fkv = *(const v8s*)&fkT[m8 * 72 + kk * 32 + quad * 8];
        v8s bfrag;
        float kss = 0.f;
#pragma unroll
        for (int j = 0; j < 8; ++j) {
          const float v = bf2f((unsigned short)pkv[j]) * bf2f((unsigned short)fkv[j]);
          kss += v;
          bfrag[j] = (short)f2bf(v);
        }
        ks[nt] += kss;
#pragma unroll
        for (int mt = 0; mt < 4; ++mt)
          acc[mt][nt] = __builtin_amdgcn_mfma_f32_16x16x32_bf16(a[mt], bfrag, acc[mt][nt], 0, 0, 0);
      }
    }
  }
  const size_t base = (size_t)(c * BH_ + bh) * D_ * F_;
#pragma unroll
  for (int nt = 0; nt < 4; ++nt) {
    const int pm = nb + nt * 16 + col;
#pragma unroll
    for (int mt = 0; mt < 4; ++mt) {
#pragma unroll
      for (int r = 0; r < 4; ++r) {
        const int d = mt * 16 + quad * 4 + r;
        kvch[base + (size_t)d * F_ + pm] = f2bf(acc[mt][nt][r]);
      }
    }
    float kv_ = ks[nt];
    kv_ += __shfl_xor(kv_, 16);
    kv_ += __shfl_xor(kv_, 32);
    if (quad == 0) ksum[(size_t)(c * BH_ + bh) * F_ + pm] = kv_;
  }
}

// ---------------------------------------------------------------------------
__global__ __launch_bounds__(256) void k_scan_kv(unsigned short* __restrict__ kvch) {
  const size_t s = (size_t)blockIdx.x * 256 + threadIdx.x;
  const size_t stride = (size_t)BH_ * D_ * F_;
  unsigned short v[NC_];
#pragma unroll
  for (int c = 0; c < NC_; ++c) v[c] = kvch[(size_t)c * stride + s];
  float run = 0.f;
#pragma unroll
  for (int c = 0; c < NC_; ++c) {
    const float t = bf2f(v[c]);
    kvch[(size_t)c * stride + s] = f2bf(run);
    run += t;
  }
}

__global__ __launch_bounds__(256) void k_scan_ks(float* __restrict__ ksum) {
  const int s = blockIdx.x * 256 + threadIdx.x;
  const int stride = BH_ * F_;
  float v[NC_];
#pragma unroll
  for (int c = 0; c < NC_; ++c) v[c] = ksum[c * stride + s];
  float run = 0.f;
#pragma unroll
  for (int c = 0; c < NC_; ++c) {
    const float t = v[c];
    ksum[c * stride + s] = run;
    run += t;
  }
}

// ---------------------------------------------------------------------------
// Fused scores+intra via MFMA (unchanged from round 6)
// ---------------------------------------------------------------------------
__global__ __launch_bounds__(256) void k_sintra(
    const unsigned short* __restrict__ pqb, const unsigned short* __restrict__ fqb,
    const unsigned short* __restrict__ pkb, const unsigned short* __restrict__ fkb,
    const unsigned short* __restrict__ vbf, float* __restrict__ obuf,
    float* __restrict__ nrmbuf) {
  __shared__ __align__(16) unsigned short S_lds[128 * 136];
  __shared__ __align__(16) unsigned short VT[64 * 136];
  __shared__ float fk_lds[128][8];
  const int bh = blockIdx.x & (BH_ - 1);
  const int tq = blockIdx.x >> 5;
  const int c = tq >> 1, h2 = tq & 1;
  const size_t rowT = (size_t)bh * T_ + (size_t)tq * 128;
  const size_t rowC = (size_t)bh * T_ + (size_t)c * CH_;
  const int tid = threadIdx.x, lane = tid & 63, w = tid >> 6;
  const int col = lane & 15, quad = lane >> 4;

  v8s bq[2][2];
  float fqr[2][8];
#pragma unroll
  for (int i = 0; i < 2; ++i) {
    const size_t qrow = rowT + (2 * w + i) * 16 + col;
    bq[i][0] = *(const v8s*)(pqb + qrow * P_ + quad * 8);
    bq[i][1] = *(const v8s*)(pqb + qrow * P_ + 32 + quad * 8);
    const v8s fv = *(const v8s*)(fqb + qrow * M_);
#pragma unroll
    for (int j = 0; j < 8; ++j) fqr[i][j] = bf2f((unsigned short)fv[j]);
  }
  f32x4 acc[2][4] = {};
  float rs[2] = {0.f, 0.f};

  const int vd = tid & 63, vg = tid >> 6;

  for (int sl = 0; sl <= h2; ++sl) {
    const size_t rowS = rowC + (size_t)sl * 128;
    __syncthreads();
    if (tid < 128) {
      const v8s fv = *(const v8s*)(fkb + (rowS + tid) * M_);
#pragma unroll
      for (int j = 0; j < 8; ++j) fk_lds[tid][j] = bf2f((unsigned short)fv[j]);
    }
#pragma unroll
    for (int j8 = 0; j8 < 4; ++j8) {
      const int s0 = vg * 32 + j8 * 8;
      v8s pv;
#pragma unroll
      for (int k = 0; k < 8; ++k)
        pv[k] = (short)vbf[(rowS + s0 + k) * D_ + vd];
      *(v8s*)&VT[vd * 136 + s0] = pv;
    }
    __syncthreads();
#pragma unroll
    for (int i = 0; i < 2; ++i) {
      const int tt = 2 * w + i;
      const int t_rel = h2 * 128 + tt * 16 + col;
      for (int si = 0; si < 8; ++si) {
        const size_t ar = rowS + si * 16 + col;
        const v8s a0 = *(const v8s*)(pkb + ar * P_ + quad * 8);
        const v8s a1 = *(const v8s*)(pkb + ar * P_ + 32 + quad * 8);
        f32x4 sp = {};
        sp = __builtin_amdgcn_mfma_f32_16x16x32_bf16(a0, bq[i][0], sp, 0, 0, 0);
        sp = __builtin_amdgcn_mfma_f32_16x16x32_bf16(a1, bq[i][1], sp, 0, 0, 0);
        ushort4 pk4;
        float partial = 0.f;
#pragma unroll
        for (int r = 0; r < 4; ++r) {
          const int s_in = si * 16 + quad * 4 + r;
          const float4 f0 = *(const float4*)&fk_lds[s_in][0];
          const float4 f1 = *(const float4*)&fk_lds[s_in][4];
          const float sm = f0.x * fqr[i][0] + f0.y * fqr[i][1] + f0.z * fqr[i][2] +
                           f0.w * fqr[i][3] + f1.x * fqr[i][4] + f1.y * fqr[i][5] +
                           f1.z * fqr[i][6] + f1.w * fqr[i][7];
          float val = sp[r] * sm;
          const int s_rel = sl * 128 + s_in;
          val = (s_rel <= t_rel) ? val : 0.f;
          partial += val;
          ((unsigned short*)&pk4)[r] = f2bf(val);
        }
        rs[i] += partial;
        *(ushort4*)&S_lds[(tt * 16 + col) * 136 + si * 16 + quad * 4] = pk4;
      }
    }
    __syncthreads();
#pragma unroll
    for (int i = 0; i < 2; ++i) {
      const int tt = 2 * w + i;
#pragma unroll
      for (int kk = 0; kk < 4; ++kk) {
        const v8s sa = *(const v8s*)&S_lds[(tt * 16 + col) * 136 + kk * 32 + quad * 8];
#pragma unroll
        for (int dt = 0; dt < 4; ++dt) {
          const v8s vb8 = *(const v8s*)&VT[(dt * 16 + col) * 136 + kk * 32 + quad * 8];
          acc[i][dt] = __builtin_amdgcn_mfma_f32_16x16x32_bf16(sa, vb8, acc[i][dt], 0, 0, 0);
        }
      }
    }
  }
#pragma unroll
  for (int i = 0; i < 2; ++i) {
#pragma unroll
    for (int dt = 0; dt < 4; ++dt) {
#pragma unroll
      for (int r = 0; r < 4; ++r) {
        const int t = (2 * w + i) * 16 + quad * 4 + r;
        obuf[(rowT + t) * D_ + dt * 16 + col] = acc[i][dt][r];
      }
    }
    rs[i] += __shfl_xor(rs[i], 16);
    rs[i] += __shfl_xor(rs[i], 32);
  }
  if (lane < 16) {
    const size_t nbase = (size_t)(c * BH_ + bh) * CH_ + h2 * 128;
    nrmbuf[nbase + (2 * w + 0) * 16 + lane] = rs[0];
    nrmbuf[nbase + (2 * w + 1) * 16 + lane] = rs[1];
  }
}

// ---------------------------------------------------------------------------
// Hist via MFMA (unchanged)
// ---------------------------------------------------------------------------
__global__ __launch_bounds__(256) void k_hist(
    const unsigned short* __restrict__ pqb, const unsigned short* __restrict__ fqb,
    const unsigned short* __restrict__ kvch, const float* __restrict__ ksum,
    const float* __restrict__ nrmbuf, const float* __restrict__ obuf,
    unsigned short* __restrict__ obf) {
  __shared__ __align__(16) unsigned short QF_lds[128 * 72];
  __shared__ __align__(16) unsigned short KV_lds[64 * 72];
  __shared__ float kp_lds[F_];
  __shared__ float nhs[128];
  const int half = blockIdx.x & 1;
  const int bh = (blockIdx.x >> 1) & (BH_ - 1);
  const int c = blockIdx.x >> 6;
  const int b = bh >> 4, h = bh & (H_ - 1);
  const int tid = threadIdx.x, lane = tid & 63, w = tid >> 6;
  const int col = lane & 15, quad = lane >> 4;
  const size_t rowQ = (size_t)bh * T_ + (size_t)c * CH_ + half * 128;
  const size_t kvbase = (size_t)(c * BH_ + bh) * D_ * F_;

  const int tr = tid >> 1, side = tid & 1;
  float fqr[8];
  {
    const v8s fv = *(const v8s*)(fqb + (rowQ + tr) * M_);
#pragma unroll
    for (int j = 0; j < 8; ++j) fqr[j] = bf2f((unsigned short)fv[j]);
    if (tid < 128)
      *(float4*)(&kp_lds[tid * 4]) =
          *(const float4*)(ksum + (size_t)(c * BH_ + bh) * F_ + tid * 4);
  }
  f32x4 acc[2][4] = {};
  float nh_part = 0.f;
  const int gr = tid & 7, d0 = tid >> 3;

  for (int pmt = 0; pmt < 8; ++pmt) {
    __syncthreads();
#pragma unroll
    for (int pp = 0; pp < 2; ++pp) {
      const int d = d0 + pp * 32;
      *(v8s*)&KV_lds[d * 72 + gr * 8] =
          *(const v8s*)(kvch + kvbase + (size_t)d * F_ + pmt * 64 + gr * 8);
    }
    {
      const v8s pq8 = *(const v8s*)(pqb + (rowQ + tr) * P_ + pmt * 8);
#pragma unroll
      for (int pp = 0; pp < 4; ++pp) {
        const int pl = side * 4 + pp;
        const float pqf = bf2f((unsigned short)pq8[pl]);
        const int kb_ = (pmt * 8 + pl) * 8;
        v8s o;
#pragma unroll
        for (int j = 0; j < 8; ++j) {
          const float v = pqf * fqr[j];
          nh_part += v * kp_lds[kb_ + j];
          o[j] = (short)f2bf(v);
        }
        *(v8s*)&QF_lds[tr * 72 + pl * 8] = o;
      }
    }
    __syncthreads();
#pragma unroll
    for (int kk = 0; kk < 2; ++kk) {
      v8s a[2], bb[4];
#pragma unroll
      for (int i = 0; i < 2; ++i)
        a[i] = *(const v8s*)&QF_lds[((2 * w + i) * 16 + col) * 72 + kk * 32 + quad * 8];
#pragma unroll
      for (int j = 0; j < 4; ++j)
        bb[j] = *(const v8s*)&KV_lds[(j * 16 + col) * 72 + kk * 32 + quad * 8];
#pragma unroll
      for (int i = 0; i < 2; ++i)
#pragma unroll
        for (int j = 0; j < 4; ++j)
          acc[i][j] = __builtin_amdgcn_mfma_f32_16x16x32_bf16(a[i], bb[j], acc[i][j], 0, 0, 0);
    }
  }
  {
    const float nh = nh_part + __shfl_xor(nh_part, 1);
    if (!(tid & 1)) nhs[tr] = nh;
  }
  __syncthreads();
  const size_t nbase = (size_t)(c * BH_ + bh) * CH_ + half * 128;
#pragma unroll
  for (int i = 0; i < 2; ++i) {
#pragma unroll
    for (int r = 0; r < 4; ++r) {
      const int t = (2 * w + i) * 16 + quad * 4 + r;
      const float nrm = nhs[t] + nrmbuf[nbase + t] + 1e-6f;
      const float rcp = 1.0f / nrm;
#pragma unroll
      for (int j = 0; j < 4; ++j) {
        const int d = j * 16 + col;
        const float val = (obuf[(rowQ + t) * D_ + d] + acc[i][j][r]) * rcp;
        obf[(size_t)(b * T_ + c * CH_ + half * 128 + t) * E_ + h * 64 + d] = f2bf(val);
      }
    }
  }
}

// ---------------------------------------------------------------------------
// Out GEMM via MFMA (unchanged)
// ---------------------------------------------------------------------------
__global__ __launch_bounds__(256) void k_out_mfma(
    const unsigned short* __restrict__ ob, const unsigned short* __restrict__ wb,
    const float* __restrict__ bias, float* __restrict__ out) {
  __shared__ __align__(16) unsigned short As[128 * LDSA];
  __shared__ __align__(16) unsigned short Bs[128 * LDSA];
  const int bt0 = blockIdx.x * 128, j0 = blockIdx.y * 128;
  const int tid = threadIdx.x;
  const int lane = tid & 63, wave = tid >> 6;
  const int wm = (wave & 1) * 64, wn = (wave >> 1) * 64;
  const int col = lane & 15, quad = lane >> 4;
  f32x4 acc[4][4] = {};
  const int sr = tid >> 3, sg = tid & 7;

  for (int k0 = 0; k0 < E_; k0 += 64) {
    __syncthreads();
#pragma unroll
    for (int it = 0; it < 4; ++it) {
      const int r = it * 32 + sr;
      *(v8s*)&As[r * LDSA + sg * 8] =
          *(const v8s*)(ob + (size_t)(bt0 + r) * E_ + k0 + sg * 8);
      *(v8s*)&Bs[r * LDSA + sg * 8] =
          *(const v8s*)(wb + (size_t)(j0 + r) * E_ + k0 + sg * 8);
    }
    __syncthreads();
#pragma unroll
    for (int kk = 0; kk < 2; ++kk) {
      v8s af[4], bfr[4];
#pragma unroll
      for (int i = 0; i < 4; ++i) {
        af[i] = *(const v8s*)&As[(wm + i * 16 + col) * LDSA + kk * 32 + quad * 8];
        bfr[i] = *(const v8s*)&Bs[(wn + i * 16 + col) * LDSA + kk * 32 + quad * 8];
      }
#pragma unroll
      for (int i = 0; i < 4; ++i)
#pragma unroll
        for (int j = 0; j < 4; ++j)
          acc[i][j] = __builtin_amdgcn_mfma_f32_16x16x32_bf16(af[i], bfr[j], acc[i][j], 0, 0, 0);
    }
  }
#pragma unroll
  for (int j = 0; j < 4; ++j) {
    const int n = j0 + wn + j * 16 + col;
    const float bv = bias[n];
#pragma unroll
    for (int i = 0; i < 4; ++i) {
      const int mbase = bt0 + wm + i * 16 + quad * 4;
#pragma unroll
      for (int r = 0; r < 4; ++r)
        out[(size_t)(mbase + r) * E_ + n] = acc[i][j][r] + bv;
    }
  }
}

// ---------------------------------------------------------------------------
extern "C" void kernel_launch(void* const* d_in, const int* in_sizes, int n_in,
                              void* d_out, int out_size, void* d_ws, size_t ws_size,
                              hipStream_t stream) {
  (void)in_sizes; (void)n_in; (void)out_size; (void)ws_size;
  const float* x      = (const float*)d_in[0];
  const float* qkv_w  = (const float*)d_in[1];
  const float* qkv_b  = (const float*)d_in[2];
  const float* out_w  = (const float*)d_in[3];
  const float* out_b  = (const float*)d_in[4];
  const float* omega  = (const float*)d_in[5];
  const float* poly_w = (const float*)d_in[6];
  const float* qnod   = (const float*)d_in[7];
  const float* qwt    = (const float*)d_in[8];
  float* ws = (float*)d_ws;
  float* qb   = ws + OFF_Q;
  float* kb   = ws + OFF_K;
  unsigned short* vbf = (unsigned short*)(ws + OFF_V);
  unsigned short* fqb = (unsigned short*)(ws + OFF_FQ);
  unsigned short* fkb = (unsigned short*)(ws + OFF_FK);
  float* ksb  = ws + OFF_KS;
  float* nrmb = ws + OFF_NRM;
  float* ob   = ws + OFF_O;
  unsigned short* kvb = (unsigned short*)(ws + OFF_KV);
  unsigned short* pqb = kvb + 16777216;
  unsigned short* pkb = pqb + SZ_BHTD;
  unsigned short* xhi  = kvb;
  unsigned short* xlo  = kvb + SZ_BHTD;
  unsigned short* wqkv = kvb + 2 * SZ_BHTD;
  unsigned short* obf   = (unsigned short*)kb;
  unsigned short* woutb = (unsigned short*)(ws + OFF_V);  // over dead v (post-sintra)
  float* outp = (float*)d_out;

  hipLaunchKernelGGL(k_split_x, dim3(8192), dim3(256), 0, stream, x, xhi, xlo);
  hipLaunchKernelGGL(k_cast_w, dim3(3072), dim3(256), 0, stream, qkv_w, wqkv);
  hipLaunchKernelGGL(k_qk_mfma, dim3(BT_ / 128, 16), dim3(256), 0, stream,
                     xhi, xlo, wqkv, qkv_b, qb, kb);
  hipLaunchKernelGGL(k_v_mfma, dim3(BT_ / 128, 8), dim3(256), 0, stream,
                     xhi, wqkv, qkv_b, vbf);
  hipLaunchKernelGGL(k_feat_mfma, dim3(1024), dim3(256), 0, stream,
                     qb, poly_w, omega, qnod, qwt, pqb, fqb);
  hipLaunchKernelGGL(k_feat_mfma, dim3(1024), dim3(256), 0, stream,
                     kb, poly_w, omega, qnod, qwt, pkb, fkb);
  hipLaunchKernelGGL(k_phaseA, dim3(NC_ * BH_), dim3(512), 0, stream,
                     pkb, fkb, vbf, kvb, ksb);
  hipLaunchKernelGGL(k_scan_kv, dim3(4096), dim3(256), 0, stream, kvb);
  hipLaunchKernelGGL(k_scan_ks, dim3(64), dim3(256), 0, stream, ksb);
  hipLaunchKernelGGL(k_sintra, dim3(BH_ * 32), dim3(256), 0, stream,
                     pqb, fqb, pkb, fkb, vbf, ob, nrmb);
  hipLaunchKernelGGL(k_cast_w, dim3(1024), dim3(256), 0, stream, out_w, woutb);
  hipLaunchKernelGGL(k_hist, dim3(NC_ * BH_ * 2), dim3(256), 0, stream,
                     pqb, fqb, kvb, ksb, nrmb, ob, obf);
  hipLaunchKernelGGL(k_out_mfma, dim3(BT_ / 128, E_ / 128), dim3(256), 0, stream,
                     obf, woutb, out_b, outp);
}